// Round 1
// baseline (424.517 us; speedup 1.0000x reference)
//
#include <hip/hip_runtime.h>

#define NP 250000   // P: permutations
#define NN 100000   // N: nodes
#define NE 400000   // E: edges
#define LL 16
#define DD 16

__device__ __forceinline__ float4 fma4(float a, float4 b, float4 c) {
    float4 r;
    r.x = fmaf(a, b.x, c.x);
    r.y = fmaf(a, b.y, c.y);
    r.z = fmaf(a, b.z, c.z);
    r.w = fmaf(a, b.w, c.w);
    return r;
}

// weights [d][c][l] (flat d*256 + c*16 + l) -> wt [l][d][c] (flat l*256 + d*16 + c)
__global__ void transpose_w_kernel(const float* __restrict__ w, float* __restrict__ wt) {
    int i = blockIdx.x * 256 + threadIdx.x;
    if (i < 4096) {
        int l = i & 15;
        int c = (i >> 4) & 15;
        int d = i >> 8;
        wt[l * 256 + d * 16 + c] = w[i];
    }
}

__device__ __forceinline__ void do_l(int l, int nc, float nvs, int ec, float evs,
                                     const float* __restrict__ nfeat,
                                     const int* __restrict__ efeat_idx,
                                     const float* __restrict__ bond_emb,
                                     const float* __restrict__ wt,
                                     float4 acc[4]) {
    int be = efeat_idx[ec];
    const float4* nf = (const float4*)(nfeat + (size_t)nc * DD);
    const float4* bf = (const float4*)(bond_emb + be * DD);
    float xa[16];
#pragma unroll
    for (int q = 0; q < 4; ++q) {
        float4 nq = nf[q];
        float4 bq = bf[q];
        xa[q * 4 + 0] = fmaf(nvs, nq.x, evs * bq.x);
        xa[q * 4 + 1] = fmaf(nvs, nq.y, evs * bq.y);
        xa[q * 4 + 2] = fmaf(nvs, nq.z, evs * bq.z);
        xa[q * 4 + 3] = fmaf(nvs, nq.w, evs * bq.w);
    }
    const float4* wl = (const float4*)(wt + l * 256);
#pragma unroll
    for (int d = 0; d < 16; ++d) {
        float xv = xa[d];
        acc[0] = fma4(xv, wl[d * 4 + 0], acc[0]);
        acc[1] = fma4(xv, wl[d * 4 + 1], acc[1]);
        acc[2] = fma4(xv, wl[d * 4 + 2], acc[2]);
        acc[3] = fma4(xv, wl[d * 4 + 3], acc[3]);
    }
}

__global__ __launch_bounds__(256) void perm_kernel(
    const float* __restrict__ nfeat,     // [N,16]
    const int* __restrict__ efeat_idx,   // [E]
    const int* __restrict__ n_col,       // [M]
    const float* __restrict__ n_val,     // [M]
    const int* __restrict__ e_col,       // [M]
    const float* __restrict__ e_val,     // [M]
    const int* __restrict__ p_row,       // [P]
    const float* __restrict__ p_val,     // [P]
    const float* __restrict__ wt,        // [16][16][16] transposed weights
    const float* __restrict__ bias,      // [16]
    const float* __restrict__ bond_emb,  // [4,16]
    float* __restrict__ out)             // [N,16] zero-initialized
{
    int p = blockIdx.x * 256 + threadIdx.x;
    if (p >= NP) return;

    float4 acc[4];
    acc[0] = ((const float4*)bias)[0];
    acc[1] = ((const float4*)bias)[1];
    acc[2] = ((const float4*)bias)[2];
    acc[3] = ((const float4*)bias)[3];

    const int base = p * LL;
#pragma unroll
    for (int l0 = 0; l0 < LL; l0 += 4) {
        int4 nc = *(const int4*)(n_col + base + l0);
        float4 nv = *(const float4*)(n_val + base + l0);
        int4 ec = *(const int4*)(e_col + base + l0);
        float4 ev = *(const float4*)(e_val + base + l0);
        do_l(l0 + 0, nc.x, nv.x, ec.x, ev.x, nfeat, efeat_idx, bond_emb, wt, acc);
        do_l(l0 + 1, nc.y, nv.y, ec.y, ev.y, nfeat, efeat_idx, bond_emb, wt, acc);
        do_l(l0 + 2, nc.z, nv.z, ec.z, ev.z, nfeat, efeat_idx, bond_emb, wt, acc);
        do_l(l0 + 3, nc.w, nv.w, ec.w, ev.w, nfeat, efeat_idx, bond_emb, wt, acc);
    }

    // relu, scale by p_val, scatter into out[p_row[p]]
    float pv = p_val[p];
    int dst = p_row[p] * DD;
    float r[16];
    r[0] = fmaxf(acc[0].x, 0.f); r[1] = fmaxf(acc[0].y, 0.f);
    r[2] = fmaxf(acc[0].z, 0.f); r[3] = fmaxf(acc[0].w, 0.f);
    r[4] = fmaxf(acc[1].x, 0.f); r[5] = fmaxf(acc[1].y, 0.f);
    r[6] = fmaxf(acc[1].z, 0.f); r[7] = fmaxf(acc[1].w, 0.f);
    r[8] = fmaxf(acc[2].x, 0.f); r[9] = fmaxf(acc[2].y, 0.f);
    r[10] = fmaxf(acc[2].z, 0.f); r[11] = fmaxf(acc[2].w, 0.f);
    r[12] = fmaxf(acc[3].x, 0.f); r[13] = fmaxf(acc[3].y, 0.f);
    r[14] = fmaxf(acc[3].z, 0.f); r[15] = fmaxf(acc[3].w, 0.f);
#pragma unroll
    for (int c = 0; c < 16; ++c) {
        unsafeAtomicAdd(&out[dst + c], pv * r[c]);
    }
}

__global__ __launch_bounds__(256) void gate_kernel(
    const float* __restrict__ degs,  // [N]
    const float* __restrict__ W0,    // [1,32]
    const float* __restrict__ b0,    // [32]
    const float* __restrict__ W1,    // [32,16]
    const float* __restrict__ b1,    // [16]
    float* __restrict__ out)         // [N,16] in-place multiply
{
    int n = blockIdx.x * 256 + threadIdx.x;
    if (n >= NN) return;
    float dg = degs[n];

    float4 fd[4];
    fd[0] = ((const float4*)b1)[0];
    fd[1] = ((const float4*)b1)[1];
    fd[2] = ((const float4*)b1)[2];
    fd[3] = ((const float4*)b1)[3];

#pragma unroll
    for (int j = 0; j < 32; ++j) {
        float h = fmaxf(fmaf(dg, W0[j], b0[j]), 0.f);
        const float4* w1r = (const float4*)(W1 + j * 16);
        fd[0] = fma4(h, w1r[0], fd[0]);
        fd[1] = fma4(h, w1r[1], fd[1]);
        fd[2] = fma4(h, w1r[2], fd[2]);
        fd[3] = fma4(h, w1r[3], fd[3]);
    }

    float4* o = (float4*)(out + (size_t)n * DD);
#pragma unroll
    for (int q = 0; q < 4; ++q) {
        float4 v = o[q];
        v.x *= fd[q].x;
        v.y *= fd[q].y;
        v.z *= fd[q].z;
        v.w *= fd[q].w;
        o[q] = v;
    }
}

extern "C" void kernel_launch(void* const* d_in, const int* in_sizes, int n_in,
                              void* d_out, int out_size, void* d_ws, size_t ws_size,
                              hipStream_t stream) {
    const float* nfeat     = (const float*)d_in[0];
    const int*   efeat_idx = (const int*)d_in[1];
    // d_in[2] n_row = arange(M), unused
    const int*   n_col     = (const int*)d_in[3];
    const float* n_val     = (const float*)d_in[4];
    // d_in[5] e_row = arange(M), unused
    const int*   e_col     = (const int*)d_in[6];
    const float* e_val     = (const float*)d_in[7];
    const int*   p_row     = (const int*)d_in[8];
    // d_in[9] p_col = arange(P), unused
    const float* p_val     = (const float*)d_in[10];
    const float* degs      = (const float*)d_in[11];
    const float* weights   = (const float*)d_in[12];
    const float* bias      = (const float*)d_in[13];
    const float* W0        = (const float*)d_in[14];
    const float* b0        = (const float*)d_in[15];
    const float* W1        = (const float*)d_in[16];
    const float* b1        = (const float*)d_in[17];
    const float* bond_emb  = (const float*)d_in[18];

    float* out = (float*)d_out;
    float* wt  = (float*)d_ws;  // 4096 floats

    hipMemsetAsync(d_out, 0, (size_t)NN * DD * sizeof(float), stream);
    transpose_w_kernel<<<16, 256, 0, stream>>>(weights, wt);
    perm_kernel<<<(NP + 255) / 256, 256, 0, stream>>>(
        nfeat, efeat_idx, n_col, n_val, e_col, e_val, p_row, p_val,
        wt, bias, bond_emb, out);
    gate_kernel<<<(NN + 255) / 256, 256, 0, stream>>>(degs, W0, b0, W1, b1, out);
}

// Round 2
// 274.515 us; speedup vs baseline: 1.5464x; 1.5464x over previous
//
#include <hip/hip_runtime.h>

#define NP 250000   // P: permutations
#define NN 100000   // N: nodes
#define NE 400000   // E: edges
#define LL 16
#define DD 16

#define WT_STRIDE 260   // 16 floats/row * 16 rows + pad: 4*l mod 32 gives 2 bank groups -> free
#define BW_STRIDE 68

__device__ __forceinline__ float4 fma4(float a, float4 b, float4 c) {
    float4 r;
    r.x = fmaf(a, b.x, c.x);
    r.y = fmaf(a, b.y, c.y);
    r.z = fmaf(a, b.z, c.z);
    r.w = fmaf(a, b.w, c.w);
    return r;
}

// wtp[l*260 + d*16 + c] = weights[d*256 + c*16 + l]   (4160 floats, pads zeroed)
// bw[l*64 + be*16 + c]  = sum_d bond_emb[be][d] * weights[d*256 + c*16 + l]  (1024 floats)
__global__ void precompute_kernel(const float* __restrict__ w,
                                  const float* __restrict__ bond_emb,
                                  float* __restrict__ wtp,
                                  float* __restrict__ bw) {
    int i = blockIdx.x * 256 + threadIdx.x;
    if (i < 16 * WT_STRIDE) {
        int l = i / WT_STRIDE;
        int r = i - l * WT_STRIDE;
        if (r < 256) {
            int d = r >> 4, c = r & 15;
            wtp[i] = w[d * 256 + c * 16 + l];
        } else {
            wtp[i] = 0.f;
        }
    }
    if (i < 1024) {
        int l = i >> 6;
        int rb = i & 63;
        int be = rb >> 4, c = rb & 15;
        float s = 0.f;
#pragma unroll
        for (int d = 0; d < 16; ++d)
            s += bond_emb[be * 16 + d] * w[d * 256 + c * 16 + l];
        bw[i] = s;
    }
}

// 4 threads per perm; thread sub handles rows l = sub*4 .. sub*4+3.
__global__ __launch_bounds__(256) void perm_kernel(
    const float* __restrict__ nfeat,     // [N,16]
    const int* __restrict__ efeat_idx,   // [E]
    const int* __restrict__ n_col,       // [M]
    const float* __restrict__ n_val,     // [M]
    const int* __restrict__ e_col,       // [M]
    const float* __restrict__ e_val,     // [M]
    const int* __restrict__ p_row,       // [P]
    const float* __restrict__ p_val,     // [P]
    const float* __restrict__ wtp,       // [16*260]
    const float* __restrict__ bw,        // [16*64]
    const float* __restrict__ bias,      // [16]
    float* __restrict__ out)             // [N,16] zero-initialized
{
    __shared__ float swt[16 * WT_STRIDE];
    __shared__ float sbw[16 * BW_STRIDE];
    for (int i = threadIdx.x; i < 16 * WT_STRIDE; i += 256) swt[i] = wtp[i];
    for (int i = threadIdx.x; i < 1024; i += 256) {
        int l = i >> 6, r = i & 63;
        sbw[l * BW_STRIDE + r] = bw[i];
    }
    __syncthreads();

    int t = blockIdx.x * 256 + threadIdx.x;
    int p = t >> 2;
    if (p >= NP) return;
    int sub = t & 3;
    int base = p * LL + sub * 4;

    // independent loads first -> max memory-level parallelism
    int4 nc = *(const int4*)(n_col + base);
    float4 nv = *(const float4*)(n_val + base);
    int4 ec = *(const int4*)(e_col + base);
    float4 ev = *(const float4*)(e_val + base);
    float pv = p_val[p];
    int prow = p_row[p];

    int be[4];
    be[0] = efeat_idx[ec.x];
    be[1] = efeat_idx[ec.y];
    be[2] = efeat_idx[ec.z];
    be[3] = efeat_idx[ec.w];

    float4 nf[4][4];
    {
        const float4* s0 = (const float4*)(nfeat + (size_t)nc.x * DD);
        const float4* s1 = (const float4*)(nfeat + (size_t)nc.y * DD);
        const float4* s2 = (const float4*)(nfeat + (size_t)nc.z * DD);
        const float4* s3 = (const float4*)(nfeat + (size_t)nc.w * DD);
#pragma unroll
        for (int q = 0; q < 4; ++q) {
            nf[0][q] = s0[q];
            nf[1][q] = s1[q];
            nf[2][q] = s2[q];
            nf[3][q] = s3[q];
        }
    }

    float nvs[4] = {nv.x, nv.y, nv.z, nv.w};
    float evs[4] = {ev.x, ev.y, ev.z, ev.w};

    float4 acc[4];
    acc[0] = make_float4(0.f, 0.f, 0.f, 0.f);
    acc[1] = make_float4(0.f, 0.f, 0.f, 0.f);
    acc[2] = make_float4(0.f, 0.f, 0.f, 0.f);
    acc[3] = make_float4(0.f, 0.f, 0.f, 0.f);

#pragma unroll
    for (int j = 0; j < 4; ++j) {
        int l = sub * 4 + j;
        const float* wl = &swt[l * WT_STRIDE];
        float x[16];
#pragma unroll
        for (int q = 0; q < 4; ++q) {
            x[q * 4 + 0] = nvs[j] * nf[j][q].x;
            x[q * 4 + 1] = nvs[j] * nf[j][q].y;
            x[q * 4 + 2] = nvs[j] * nf[j][q].z;
            x[q * 4 + 3] = nvs[j] * nf[j][q].w;
        }
#pragma unroll
        for (int d = 0; d < 16; ++d) {
            const float4* wr = (const float4*)&wl[d * 16];
            float xd = x[d];
            acc[0] = fma4(xd, wr[0], acc[0]);
            acc[1] = fma4(xd, wr[1], acc[1]);
            acc[2] = fma4(xd, wr[2], acc[2]);
            acc[3] = fma4(xd, wr[3], acc[3]);
        }
        const float4* bl = (const float4*)&sbw[l * BW_STRIDE + be[j] * 16];
        float evj = evs[j];
        acc[0] = fma4(evj, bl[0], acc[0]);
        acc[1] = fma4(evj, bl[1], acc[1]);
        acc[2] = fma4(evj, bl[2], acc[2]);
        acc[3] = fma4(evj, bl[3], acc[3]);
    }

    // butterfly-reduce across the 4 lanes of this perm (all lanes end with full sum)
    float a[16];
#pragma unroll
    for (int q = 0; q < 4; ++q) {
        a[q * 4 + 0] = acc[q].x;
        a[q * 4 + 1] = acc[q].y;
        a[q * 4 + 2] = acc[q].z;
        a[q * 4 + 3] = acc[q].w;
    }
#pragma unroll
    for (int off = 1; off < 4; off <<= 1) {
#pragma unroll
        for (int c = 0; c < 16; ++c) {
            a[c] += __shfl_xor(a[c], off, 64);
        }
    }

    // lane `sub` commits channels sub*4..sub*4+3
    float4 b = ((const float4*)bias)[sub];
    float vx = fmaxf(a[sub * 4 + 0] + b.x, 0.f) * pv;
    float vy = fmaxf(a[sub * 4 + 1] + b.y, 0.f) * pv;
    float vz = fmaxf(a[sub * 4 + 2] + b.z, 0.f) * pv;
    float vw = fmaxf(a[sub * 4 + 3] + b.w, 0.f) * pv;

    float* dst = out + (size_t)prow * DD + sub * 4;
    unsafeAtomicAdd(dst + 0, vx);
    unsafeAtomicAdd(dst + 1, vy);
    unsafeAtomicAdd(dst + 2, vz);
    unsafeAtomicAdd(dst + 3, vw);
}

__global__ __launch_bounds__(256) void gate_kernel(
    const float* __restrict__ degs,  // [N]
    const float* __restrict__ W0,    // [1,32]
    const float* __restrict__ b0,    // [32]
    const float* __restrict__ W1,    // [32,16]
    const float* __restrict__ b1,    // [16]
    float* __restrict__ out)         // [N,16] in-place multiply
{
    int n = blockIdx.x * 256 + threadIdx.x;
    if (n >= NN) return;
    float dg = degs[n];

    float4 fd[4];
    fd[0] = ((const float4*)b1)[0];
    fd[1] = ((const float4*)b1)[1];
    fd[2] = ((const float4*)b1)[2];
    fd[3] = ((const float4*)b1)[3];

#pragma unroll
    for (int j = 0; j < 32; ++j) {
        float h = fmaxf(fmaf(dg, W0[j], b0[j]), 0.f);
        const float4* w1r = (const float4*)(W1 + j * 16);
        fd[0] = fma4(h, w1r[0], fd[0]);
        fd[1] = fma4(h, w1r[1], fd[1]);
        fd[2] = fma4(h, w1r[2], fd[2]);
        fd[3] = fma4(h, w1r[3], fd[3]);
    }

    float4* o = (float4*)(out + (size_t)n * DD);
#pragma unroll
    for (int q = 0; q < 4; ++q) {
        float4 v = o[q];
        v.x *= fd[q].x;
        v.y *= fd[q].y;
        v.z *= fd[q].z;
        v.w *= fd[q].w;
        o[q] = v;
    }
}

extern "C" void kernel_launch(void* const* d_in, const int* in_sizes, int n_in,
                              void* d_out, int out_size, void* d_ws, size_t ws_size,
                              hipStream_t stream) {
    const float* nfeat     = (const float*)d_in[0];
    const int*   efeat_idx = (const int*)d_in[1];
    // d_in[2] n_row = arange(M), unused
    const int*   n_col     = (const int*)d_in[3];
    const float* n_val     = (const float*)d_in[4];
    // d_in[5] e_row = arange(M), unused
    const int*   e_col     = (const int*)d_in[6];
    const float* e_val     = (const float*)d_in[7];
    const int*   p_row     = (const int*)d_in[8];
    // d_in[9] p_col = arange(P), unused
    const float* p_val     = (const float*)d_in[10];
    const float* degs      = (const float*)d_in[11];
    const float* weights   = (const float*)d_in[12];
    const float* bias      = (const float*)d_in[13];
    const float* W0        = (const float*)d_in[14];
    const float* b0        = (const float*)d_in[15];
    const float* W1        = (const float*)d_in[16];
    const float* b1        = (const float*)d_in[17];
    const float* bond_emb  = (const float*)d_in[18];

    float* out = (float*)d_out;
    float* wtp = (float*)d_ws;             // 16*260 = 4160 floats
    float* bw  = wtp + 16 * WT_STRIDE;     // 1024 floats

    hipMemsetAsync(d_out, 0, (size_t)NN * DD * sizeof(float), stream);
    precompute_kernel<<<17, 256, 0, stream>>>(weights, bond_emb, wtp, bw);

    int nthreads = NP * 4;
    perm_kernel<<<(nthreads + 255) / 256, 256, 0, stream>>>(
        nfeat, efeat_idx, n_col, n_val, e_col, e_val, p_row, p_val,
        wtp, bw, bias, out);
    gate_kernel<<<(NN + 255) / 256, 256, 0, stream>>>(degs, W0, b0, W1, b1, out);
}